// Round 2
// baseline (6863.946 us; speedup 1.0000x reference)
//
#include <hip/hip_runtime.h>

#define IN_DIM   320
#define POOL_DIM 256
#define HID      128
#define BM       128
#define BK       32
#define NKC      (IN_DIM / BK)   // 10

typedef __attribute__((address_space(1))) const unsigned int guint;
typedef __attribute__((address_space(3))) unsigned int luint;

__device__ __forceinline__ void gl_lds16(const float* g, float* l) {
    __builtin_amdgcn_global_load_lds((guint*)g, (luint*)l, 16, 0, 0);
}

// ---------------------------------------------------------------------------
// Kernel A: scores = relu(z @ W1^T + b1) @ W2^T + b2      [N]
// Block tile: 128 rows x 128 h, K chunked by 32. Per-thread 8x8 register tile.
// Staging via global_load_lds (linear LDS dest, swizzle applied to the GLOBAL
// source quad index):
//   zs[row][slot], slot = q ^ ((row>>3)&7)  -> za reads: 4 addrs in 4 bank
//       groups, 16-way broadcast each => conflict-free
//   ws[h][slot],   slot = q ^ (h&7)         -> wb reads: 2-way (b128 floor)
// ---------------------------------------------------------------------------
__global__ __launch_bounds__(256, 3) void attn_scores_kernel(
    const float* __restrict__ z, const float* __restrict__ W1,
    const float* __restrict__ b1, const float* __restrict__ W2,
    const float* __restrict__ b2,
    float* __restrict__ scores, float* __restrict__ bmax,
    float* __restrict__ bsum, int N)
{
    __shared__ float zs[BM * BK];     // 16 KB
    __shared__ float ws[HID * BK];    // 16 KB
    __shared__ float sblk[BM];

    const int tid = threadIdx.x;
    const int tx  = tid & 15;         // h-lane (16)
    const int ty  = tid >> 4;         // row-group (16)
    const int r0  = blockIdx.x * BM;

    float acc[8][8];
#pragma unroll
    for (int a = 0; a < 8; a++)
#pragma unroll
        for (int b = 0; b < 8; b++) acc[a][b] = 0.f;

    // staging descriptors: 4 rounds each for z and W1; round j covers
    // linear LDS slot t = j*256 + tid (16B per slot)
    const float* zp[4]; const float* wp[4];
    float* zd[4]; float* wd[4];
#pragma unroll
    for (int j = 0; j < 4; ++j) {
        const int t   = j * 256 + tid;
        const int row = t >> 3;                       // 0..127
        const int zq  = (t & 7) ^ ((t >> 6) & 7);     // source quad (z swizzle)
        int gr = r0 + row; if (gr > N - 1) gr = N - 1;
        zp[j] = z + (size_t)gr * IN_DIM + zq * 4;
        zd[j] = &zs[t * 4];
        const int wq = (t & 7) ^ ((t >> 3) & 7);      // source quad (W1 swizzle)
        wp[j] = W1 + (size_t)row * IN_DIM + wq * 4;   // h = row
        wd[j] = &ws[t * 4];
    }

    const float4* zs4 = (const float4*)zs;
    const float4* ws4 = (const float4*)ws;
    const int tym = ty & 7;
    const int txm = tx & 7;

    for (int kc = 0; kc < NKC; ++kc) {
        const int k0 = kc * BK;
#pragma unroll
        for (int j = 0; j < 4; ++j) gl_lds16(zp[j] + k0, zd[j]);
#pragma unroll
        for (int j = 0; j < 4; ++j) gl_lds16(wp[j] + k0, wd[j]);
        __syncthreads();

#pragma unroll
        for (int q = 0; q < 8; ++q) {
            const int zslot = q ^ tym;
            const int wslot = q ^ txm;
            float4 za[8];
#pragma unroll
            for (int rr = 0; rr < 8; ++rr)
                za[rr] = zs4[(ty * 8 + rr) * 8 + zslot];
#pragma unroll
            for (int hh = 0; hh < 8; ++hh) {
                const float4 wb = ws4[(hh * 16 + tx) * 8 + wslot];
#pragma unroll
                for (int rr = 0; rr < 8; ++rr) {
                    acc[rr][hh] += za[rr].x * wb.x + za[rr].y * wb.y +
                                   za[rr].z * wb.z + za[rr].w * wb.w;
                }
            }
        }
        __syncthreads();
    }

    // ---- epilogue: relu, dot with W2, reduce over the 16 tx lanes
    float b1v[8], w2v[8];
#pragma unroll
    for (int hh = 0; hh < 8; hh++) {
        b1v[hh] = b1[hh * 16 + tx];
        w2v[hh] = W2[hh * 16 + tx];
    }
    const float b2v = b2[0];

#pragma unroll
    for (int rr = 0; rr < 8; rr++) {
        float s = 0.f;
#pragma unroll
        for (int hh = 0; hh < 8; hh++) {
            const float hv = acc[rr][hh] + b1v[hh];
            s += fmaxf(hv, 0.f) * w2v[hh];
        }
#pragma unroll
        for (int d = 1; d < 16; d <<= 1) s += __shfl_xor(s, d, 16);
        s += b2v;
        if (tx == 0) {
            const int r = ty * 8 + rr;
            if (r0 + r < N) {
                scores[r0 + r] = s;
                sblk[r] = s;
            } else {
                sblk[r] = -1e30f;
            }
        }
    }
    __syncthreads();

    // ---- block (max, sum-exp): 128 scores folded into one wave
    if (tid < 64) {
        const float v0 = sblk[tid];
        const float v1 = sblk[tid + 64];
        float m = fmaxf(v0, v1);
#pragma unroll
        for (int d = 1; d < 64; d <<= 1) m = fmaxf(m, __shfl_xor(m, d, 64));
        float e = __expf(v0 - m) + __expf(v1 - m);
#pragma unroll
        for (int d = 1; d < 64; d <<= 1) e += __shfl_xor(e, d, 64);
        if (tid == 0) {
            bmax[blockIdx.x] = m;
            bsum[blockIdx.x] = e;
        }
    }
}

// ---------------------------------------------------------------------------
// Kernel B: combine per-block (max, sumexp) -> global max & softmax denom
// ---------------------------------------------------------------------------
__global__ __launch_bounds__(256) void softmax_reduce_kernel(
    const float* __restrict__ bmax, const float* __restrict__ bsum,
    float* __restrict__ red, int nb)
{
    __shared__ float sm[4];
    __shared__ float ss[4];
    const int tid = threadIdx.x;

    float m = -1e30f;
    for (int i = tid; i < nb; i += 256) m = fmaxf(m, bmax[i]);
#pragma unroll
    for (int d = 1; d < 64; d <<= 1) m = fmaxf(m, __shfl_xor(m, d, 64));
    if ((tid & 63) == 0) sm[tid >> 6] = m;
    __syncthreads();
    const float gmax = fmaxf(fmaxf(sm[0], sm[1]), fmaxf(sm[2], sm[3]));

    float s = 0.f;
    for (int i = tid; i < nb; i += 256) s += bsum[i] * __expf(bmax[i] - gmax);
#pragma unroll
    for (int d = 1; d < 64; d <<= 1) s += __shfl_xor(s, d, 64);
    if ((tid & 63) == 0) ss[tid >> 6] = s;
    __syncthreads();
    if (tid == 0) {
        red[0] = gmax;
        red[1] = ss[0] + ss[1] + ss[2] + ss[3];
    }
}

// ---------------------------------------------------------------------------
// Kernel E: per-graph weighted mean. batch_index sorted -> binary search the
// [start, end) row range; one block per graph, one thread per column.
// ---------------------------------------------------------------------------
__device__ __forceinline__ int lower_bound(const int* __restrict__ a, int n, int key)
{
    int lo = 0, hi = n;
    while (lo < hi) {
        int mid = (lo + hi) >> 1;
        if (a[mid] < key) lo = mid + 1; else hi = mid;
    }
    return lo;
}

__global__ __launch_bounds__(256) void pool_kernel(
    const float* __restrict__ z, const int* __restrict__ bidx,
    const float* __restrict__ scores, const float* __restrict__ red,
    float* __restrict__ out, int N)
{
    const int g   = blockIdx.x;
    const int col = threadIdx.x;
    __shared__ int se[2];
    if (col == 0) {
        se[0] = lower_bound(bidx, N, g);
        se[1] = lower_bound(bidx, N, g + 1);
    }
    __syncthreads();
    const int start = se[0], end = se[1];
    const float gmax    = red[0];
    const float inv_den = 1.0f / red[1];

    float a0 = 0.f, a1 = 0.f, a2 = 0.f, a3 = 0.f;
    int i = start;
    for (; i + 3 < end; i += 4) {
        const float w0 = __expf(scores[i]     - gmax);
        const float w1 = __expf(scores[i + 1] - gmax);
        const float w2 = __expf(scores[i + 2] - gmax);
        const float w3 = __expf(scores[i + 3] - gmax);
        a0 += w0 * z[(size_t)i * IN_DIM + col];
        a1 += w1 * z[(size_t)(i + 1) * IN_DIM + col];
        a2 += w2 * z[(size_t)(i + 2) * IN_DIM + col];
        a3 += w3 * z[(size_t)(i + 3) * IN_DIM + col];
    }
    for (; i < end; ++i)
        a0 += __expf(scores[i] - gmax) * z[(size_t)i * IN_DIM + col];

    const float acc = (a0 + a1) + (a2 + a3);
    const int cnt = end - start;
    out[(size_t)g * POOL_DIM + col] = acc * inv_den / fmaxf((float)cnt, 1.0f);
}

// ---------------------------------------------------------------------------
extern "C" void kernel_launch(void* const* d_in, const int* in_sizes, int n_in,
                              void* d_out, int out_size, void* d_ws, size_t ws_size,
                              hipStream_t stream)
{
    const float* z    = (const float*)d_in[0];
    const int*   bidx = (const int*)  d_in[1];
    const float* W1   = (const float*)d_in[2];
    const float* b1   = (const float*)d_in[3];
    const float* W2   = (const float*)d_in[4];
    const float* b2   = (const float*)d_in[5];
    float*       out  = (float*)d_out;

    const int N  = in_sizes[0] / IN_DIM;       // 200000
    const int G  = out_size / POOL_DIM;        // 2000
    const int nb = (N + BM - 1) / BM;          // 1563

    float* scores = (float*)d_ws;
    float* bmax   = scores + N;
    float* bsum   = bmax + nb;
    float* red    = bsum + nb;

    attn_scores_kernel<<<nb, 256, 0, stream>>>(z, W1, b1, W2, b2,
                                               scores, bmax, bsum, N);
    softmax_reduce_kernel<<<1, 256, 0, stream>>>(bmax, bsum, red, nb);
    pool_kernel<<<G, 256, 0, stream>>>(z, bidx, scores, red, out, N);
}

// Round 3
// 711.958 us; speedup vs baseline: 9.6409x; 9.6409x over previous
//
#include <hip/hip_runtime.h>

#define IN_DIM   320
#define POOL_DIM 256
#define HID      128
#define BM       128
#define BK       32
#define NKC      (IN_DIM / BK)   // 10

typedef __attribute__((address_space(1))) const unsigned int guint;
typedef __attribute__((address_space(3))) unsigned int luint;

__device__ __forceinline__ void gl_lds16(const float* g, float* l) {
    __builtin_amdgcn_global_load_lds((guint*)g, (luint*)l, 16, 0, 0);
}

// ---------------------------------------------------------------------------
// Kernel A: scores = relu(z @ W1^T + b1) @ W2^T + b2      [N]
// Block tile: 128 rows x 128 h, K chunked by 32. Per-thread 8x8 register tile.
// Staging via global_load_lds (linear LDS dest, swizzle applied to the GLOBAL
// source quad index):
//   zs[row][slot], slot = q ^ ((row>>3)&7)  -> za reads: broadcast x16,
//       4 distinct 16B slots in 4 distinct bank quads => conflict-free
//   ws[h][slot],   slot = q ^ (h&7)         -> wb reads: 2-way (free, m136)
// NOTE: plain __launch_bounds__(256). (256,3) made hipcc cap VGPR at 84 and
// spill the 8x8 accumulator to scratch -> 13 GB of scratch writes (round 2).
// ---------------------------------------------------------------------------
__global__ __launch_bounds__(256) void attn_scores_kernel(
    const float* __restrict__ z, const float* __restrict__ W1,
    const float* __restrict__ b1, const float* __restrict__ W2,
    const float* __restrict__ b2,
    float* __restrict__ scores, float* __restrict__ bmax,
    float* __restrict__ bsum, int N)
{
    __shared__ float zs[BM * BK];     // 16 KB
    __shared__ float ws[HID * BK];    // 16 KB
    __shared__ float sblk[BM];

    const int tid = threadIdx.x;
    const int tx  = tid & 15;         // h-lane (16)
    const int ty  = tid >> 4;         // row-group (16)
    const int r0  = blockIdx.x * BM;

    float acc[8][8];
#pragma unroll
    for (int a = 0; a < 8; a++)
#pragma unroll
        for (int b = 0; b < 8; b++) acc[a][b] = 0.f;

    // staging descriptors: 4 rounds each for z and W1; round j covers
    // linear LDS slot t = j*256 + tid (16B per slot)
    const float* zp[4]; const float* wp[4];
    float* zd[4]; float* wd[4];
#pragma unroll
    for (int j = 0; j < 4; ++j) {
        const int t   = j * 256 + tid;
        const int row = t >> 3;                       // 0..127
        const int zq  = (t & 7) ^ ((t >> 6) & 7);     // source quad (z swizzle)
        int gr = r0 + row; if (gr > N - 1) gr = N - 1;
        zp[j] = z + (size_t)gr * IN_DIM + zq * 4;
        zd[j] = &zs[t * 4];
        const int wq = (t & 7) ^ ((t >> 3) & 7);      // source quad (W1 swizzle)
        wp[j] = W1 + (size_t)row * IN_DIM + wq * 4;   // h = row
        wd[j] = &ws[t * 4];
    }

    const float4* zs4 = (const float4*)zs;
    const float4* ws4 = (const float4*)ws;
    const int tym = ty & 7;
    const int txm = tx & 7;

    for (int kc = 0; kc < NKC; ++kc) {
        const int k0 = kc * BK;
#pragma unroll
        for (int j = 0; j < 4; ++j) gl_lds16(zp[j] + k0, zd[j]);
#pragma unroll
        for (int j = 0; j < 4; ++j) gl_lds16(wp[j] + k0, wd[j]);
        __syncthreads();

#pragma unroll
        for (int q = 0; q < 8; ++q) {
            const int zslot = q ^ tym;
            const int wslot = q ^ txm;
            float4 za[8];
#pragma unroll
            for (int rr = 0; rr < 8; ++rr)
                za[rr] = zs4[(ty * 8 + rr) * 8 + zslot];
#pragma unroll
            for (int hh = 0; hh < 8; ++hh) {
                const float4 wb = ws4[(hh * 16 + tx) * 8 + wslot];
#pragma unroll
                for (int rr = 0; rr < 8; ++rr) {
                    acc[rr][hh] += za[rr].x * wb.x + za[rr].y * wb.y +
                                   za[rr].z * wb.z + za[rr].w * wb.w;
                }
            }
        }
        __syncthreads();
    }

    // ---- epilogue: relu, dot with W2, reduce over the 16 tx lanes
    float b1v[8], w2v[8];
#pragma unroll
    for (int hh = 0; hh < 8; hh++) {
        b1v[hh] = b1[hh * 16 + tx];
        w2v[hh] = W2[hh * 16 + tx];
    }
    const float b2v = b2[0];

#pragma unroll
    for (int rr = 0; rr < 8; rr++) {
        float s = 0.f;
#pragma unroll
        for (int hh = 0; hh < 8; hh++) {
            const float hv = acc[rr][hh] + b1v[hh];
            s += fmaxf(hv, 0.f) * w2v[hh];
        }
#pragma unroll
        for (int d = 1; d < 16; d <<= 1) s += __shfl_xor(s, d, 16);
        s += b2v;
        if (tx == 0) {
            const int r = ty * 8 + rr;
            if (r0 + r < N) {
                scores[r0 + r] = s;
                sblk[r] = s;
            } else {
                sblk[r] = -1e30f;
            }
        }
    }
    __syncthreads();

    // ---- block (max, sum-exp): 128 scores folded into one wave
    if (tid < 64) {
        const float v0 = sblk[tid];
        const float v1 = sblk[tid + 64];
        float m = fmaxf(v0, v1);
#pragma unroll
        for (int d = 1; d < 64; d <<= 1) m = fmaxf(m, __shfl_xor(m, d, 64));
        float e = __expf(v0 - m) + __expf(v1 - m);
#pragma unroll
        for (int d = 1; d < 64; d <<= 1) e += __shfl_xor(e, d, 64);
        if (tid == 0) {
            bmax[blockIdx.x] = m;
            bsum[blockIdx.x] = e;
        }
    }
}

// ---------------------------------------------------------------------------
// Kernel B: combine per-block (max, sumexp) -> global max & softmax denom
// ---------------------------------------------------------------------------
__global__ __launch_bounds__(256) void softmax_reduce_kernel(
    const float* __restrict__ bmax, const float* __restrict__ bsum,
    float* __restrict__ red, int nb)
{
    __shared__ float sm[4];
    __shared__ float ss[4];
    const int tid = threadIdx.x;

    float m = -1e30f;
    for (int i = tid; i < nb; i += 256) m = fmaxf(m, bmax[i]);
#pragma unroll
    for (int d = 1; d < 64; d <<= 1) m = fmaxf(m, __shfl_xor(m, d, 64));
    if ((tid & 63) == 0) sm[tid >> 6] = m;
    __syncthreads();
    const float gmax = fmaxf(fmaxf(sm[0], sm[1]), fmaxf(sm[2], sm[3]));

    float s = 0.f;
    for (int i = tid; i < nb; i += 256) s += bsum[i] * __expf(bmax[i] - gmax);
#pragma unroll
    for (int d = 1; d < 64; d <<= 1) s += __shfl_xor(s, d, 64);
    if ((tid & 63) == 0) ss[tid >> 6] = s;
    __syncthreads();
    if (tid == 0) {
        red[0] = gmax;
        red[1] = ss[0] + ss[1] + ss[2] + ss[3];
    }
}

// ---------------------------------------------------------------------------
// Kernel E: per-graph weighted mean. batch_index sorted -> binary search the
// [start, end) row range; one block per graph, one thread per column.
// ---------------------------------------------------------------------------
__device__ __forceinline__ int lower_bound(const int* __restrict__ a, int n, int key)
{
    int lo = 0, hi = n;
    while (lo < hi) {
        int mid = (lo + hi) >> 1;
        if (a[mid] < key) lo = mid + 1; else hi = mid;
    }
    return lo;
}

__global__ __launch_bounds__(256) void pool_kernel(
    const float* __restrict__ z, const int* __restrict__ bidx,
    const float* __restrict__ scores, const float* __restrict__ red,
    float* __restrict__ out, int N)
{
    const int g   = blockIdx.x;
    const int col = threadIdx.x;
    __shared__ int se[2];
    if (col == 0) {
        se[0] = lower_bound(bidx, N, g);
        se[1] = lower_bound(bidx, N, g + 1);
    }
    __syncthreads();
    const int start = se[0], end = se[1];
    const float gmax    = red[0];
    const float inv_den = 1.0f / red[1];

    float a0 = 0.f, a1 = 0.f, a2 = 0.f, a3 = 0.f;
    int i = start;
    for (; i + 3 < end; i += 4) {
        const float w0 = __expf(scores[i]     - gmax);
        const float w1 = __expf(scores[i + 1] - gmax);
        const float w2 = __expf(scores[i + 2] - gmax);
        const float w3 = __expf(scores[i + 3] - gmax);
        a0 += w0 * z[(size_t)i * IN_DIM + col];
        a1 += w1 * z[(size_t)(i + 1) * IN_DIM + col];
        a2 += w2 * z[(size_t)(i + 2) * IN_DIM + col];
        a3 += w3 * z[(size_t)(i + 3) * IN_DIM + col];
    }
    for (; i < end; ++i)
        a0 += __expf(scores[i] - gmax) * z[(size_t)i * IN_DIM + col];

    const float acc = (a0 + a1) + (a2 + a3);
    const int cnt = end - start;
    out[(size_t)g * POOL_DIM + col] = acc * inv_den / fmaxf((float)cnt, 1.0f);
}

// ---------------------------------------------------------------------------
extern "C" void kernel_launch(void* const* d_in, const int* in_sizes, int n_in,
                              void* d_out, int out_size, void* d_ws, size_t ws_size,
                              hipStream_t stream)
{
    const float* z    = (const float*)d_in[0];
    const int*   bidx = (const int*)  d_in[1];
    const float* W1   = (const float*)d_in[2];
    const float* b1   = (const float*)d_in[3];
    const float* W2   = (const float*)d_in[4];
    const float* b2   = (const float*)d_in[5];
    float*       out  = (float*)d_out;

    const int N  = in_sizes[0] / IN_DIM;       // 200000
    const int G  = out_size / POOL_DIM;        // 2000
    const int nb = (N + BM - 1) / BM;          // 1563

    float* scores = (float*)d_ws;
    float* bmax   = scores + N;
    float* bsum   = bmax + nb;
    float* red    = bsum + nb;

    attn_scores_kernel<<<nb, 256, 0, stream>>>(z, W1, b1, W2, b2,
                                               scores, bmax, bsum, N);
    softmax_reduce_kernel<<<1, 256, 0, stream>>>(bmax, bsum, red, nb);
    pool_kernel<<<G, 256, 0, stream>>>(z, bidx, scores, red, out, N);
}

// Round 4
// 219.532 us; speedup vs baseline: 31.2663x; 3.2431x over previous
//
#include <hip/hip_runtime.h>

#define IN_DIM   320
#define POOL_DIM 256
#define HID      128
#define RPB      128            // rows per block (4 waves x 32 rows)
#define NKC      10             // 320 / 32

typedef __attribute__((ext_vector_type(8))) short bf16x8;
typedef __attribute__((ext_vector_type(4))) float f32x4;

__device__ __forceinline__ unsigned fbits(float f) {
    union { float f; unsigned u; } c; c.f = f; return c.u;
}
// pack bf16(trunc) of two f32 bit patterns: low16 = u0>>16, high16 = u1>>16
__device__ __forceinline__ unsigned pack2(unsigned u0, unsigned u1) {
    return __builtin_amdgcn_perm(u1, u0, 0x07060302u);
}

// split 8 f32 into hi(trunc-bf16) + lo(bf16 of residual); hi+lo ~ f32 exact
// to ~2^-16 relative. 3 VALU ops per value.
__device__ __forceinline__ void split8(float4 a, float4 b, bf16x8& hi, bf16x8& lo) {
    float f[8] = { a.x, a.y, a.z, a.w, b.x, b.y, b.z, b.w };
    unsigned hu[8], lu[8];
#pragma unroll
    for (int i = 0; i < 8; ++i) {
        unsigned u = fbits(f[i]);
        hu[i] = u;
        float hif = __builtin_bit_cast(float, u & 0xffff0000u);
        lu[i] = fbits(f[i] - hif);
    }
    int4 hp, lp;
    hp.x = pack2(hu[0], hu[1]); hp.y = pack2(hu[2], hu[3]);
    hp.z = pack2(hu[4], hu[5]); hp.w = pack2(hu[6], hu[7]);
    lp.x = pack2(lu[0], lu[1]); lp.y = pack2(lu[2], lu[3]);
    lp.z = pack2(lu[4], lu[5]); lp.w = pack2(lu[6], lu[7]);
    hi = __builtin_bit_cast(bf16x8, hp);
    lo = __builtin_bit_cast(bf16x8, lp);
}

// ---------------------------------------------------------------------------
// One-time: split W1 into hi/lo bf16 arrays (row-major [HID][IN_DIM]).
// ---------------------------------------------------------------------------
__global__ __launch_bounds__(256) void split_w1_kernel(
    const float* __restrict__ W1, ushort* __restrict__ W1h,
    ushort* __restrict__ W1l, int n)
{
    int i = blockIdx.x * 256 + threadIdx.x;
    if (i < n) {
        float f = W1[i];
        unsigned u = fbits(f);
        float hif = __builtin_bit_cast(float, u & 0xffff0000u);
        W1h[i] = (ushort)(u >> 16);
        W1l[i] = (ushort)(fbits(f - hif) >> 16);
    }
}

// ---------------------------------------------------------------------------
// Kernel A (MFMA, split-bf16): scores = relu(z @ W1^T + b1) @ W2^T + b2.
// No LDS in the main loop, no barriers -> compiler free to pipeline loads.
// Wave = 32 rows (2 m-tiles of 16), 8 h-tiles, K chunks of 32.
// mfma_f32_16x16x32_bf16 layouts: A: row=l&15, k=(l>>4)*8+j (8 consecutive);
// B: col=l&15, same k; C/D: col=l&15, row=(l>>4)*4+reg.
// 3-term split product: hi*hi + lo*hi + hi*lo (drop lo*lo ~ 2^-16 rel).
// ---------------------------------------------------------------------------
__global__ __launch_bounds__(256) void attn_scores_mfma(
    const float* __restrict__ z, const ushort* __restrict__ W1h,
    const ushort* __restrict__ W1l,
    const float* __restrict__ b1, const float* __restrict__ W2,
    const float* __restrict__ b2,
    float* __restrict__ scores, float* __restrict__ bmax,
    float* __restrict__ bsum, int N)
{
    __shared__ float sblk[RPB];

    const int tid  = threadIdx.x;
    const int wid  = tid >> 6;
    const int lane = tid & 63;
    const int lm   = lane & 15;
    const int lg   = lane >> 4;
    const int r0   = blockIdx.x * RPB;
    const int wr0  = r0 + wid * 32;

    int row0 = wr0 + lm;      if (row0 > N - 1) row0 = N - 1;
    int row1 = wr0 + 16 + lm; if (row1 > N - 1) row1 = N - 1;
    const float*  zp0 = z   + (size_t)row0 * IN_DIM + lg * 8;
    const float*  zp1 = z   + (size_t)row1 * IN_DIM + lg * 8;
    const ushort* whp = W1h + (size_t)lm   * IN_DIM + lg * 8;
    const ushort* wlp = W1l + (size_t)lm   * IN_DIM + lg * 8;

    f32x4 acc[2][8];
#pragma unroll
    for (int rt = 0; rt < 2; ++rt)
#pragma unroll
        for (int ht = 0; ht < 8; ++ht) acc[rt][ht] = (f32x4){0.f, 0.f, 0.f, 0.f};

    for (int kc = 0; kc < NKC; ++kc) {
        const int ko = kc * 32;
        bf16x8 a0h, a0l, a1h, a1l;
        {
            const float4* p = (const float4*)(zp0 + ko);
            split8(p[0], p[1], a0h, a0l);
            const float4* q = (const float4*)(zp1 + ko);
            split8(q[0], q[1], a1h, a1l);
        }
#pragma unroll
        for (int ht = 0; ht < 8; ++ht) {
            const bf16x8 bh = *(const bf16x8*)(whp + (size_t)ht * 16 * IN_DIM + ko);
            const bf16x8 bl = *(const bf16x8*)(wlp + (size_t)ht * 16 * IN_DIM + ko);
            acc[0][ht] = __builtin_amdgcn_mfma_f32_16x16x32_bf16(a0h, bh, acc[0][ht], 0, 0, 0);
            acc[0][ht] = __builtin_amdgcn_mfma_f32_16x16x32_bf16(a0l, bh, acc[0][ht], 0, 0, 0);
            acc[0][ht] = __builtin_amdgcn_mfma_f32_16x16x32_bf16(a0h, bl, acc[0][ht], 0, 0, 0);
            acc[1][ht] = __builtin_amdgcn_mfma_f32_16x16x32_bf16(a1h, bh, acc[1][ht], 0, 0, 0);
            acc[1][ht] = __builtin_amdgcn_mfma_f32_16x16x32_bf16(a1l, bh, acc[1][ht], 0, 0, 0);
            acc[1][ht] = __builtin_amdgcn_mfma_f32_16x16x32_bf16(a1h, bl, acc[1][ht], 0, 0, 0);
        }
    }

    // ---- epilogue: relu + dot(W2) per lane-col, reduce over 16 cols
    float b1v[8], w2v[8];
#pragma unroll
    for (int ht = 0; ht < 8; ++ht) {
        b1v[ht] = b1[ht * 16 + lm];
        w2v[ht] = W2[ht * 16 + lm];
    }
    const float b2v = b2[0];

#pragma unroll
    for (int rt = 0; rt < 2; ++rt) {
#pragma unroll
        for (int reg = 0; reg < 4; ++reg) {
            float s = 0.f;
#pragma unroll
            for (int ht = 0; ht < 8; ++ht)
                s += fmaxf(acc[rt][ht][reg] + b1v[ht], 0.f) * w2v[ht];
            s += __shfl_xor(s, 1);
            s += __shfl_xor(s, 2);
            s += __shfl_xor(s, 4);
            s += __shfl_xor(s, 8);
            s += b2v;
            if (lm == 0) {
                const int rloc = wid * 32 + rt * 16 + lg * 4 + reg;
                const int grow = r0 + rloc;
                if (grow < N) {
                    scores[grow] = s;
                    sblk[rloc] = s;
                } else {
                    sblk[rloc] = -1e30f;
                }
            }
        }
    }
    __syncthreads();

    // ---- block (max, sum-exp): 128 scores folded into one wave
    if (tid < 64) {
        const float v0 = sblk[tid];
        const float v1 = sblk[tid + 64];
        float m = fmaxf(v0, v1);
#pragma unroll
        for (int d = 1; d < 64; d <<= 1) m = fmaxf(m, __shfl_xor(m, d, 64));
        float e = __expf(v0 - m) + __expf(v1 - m);
#pragma unroll
        for (int d = 1; d < 64; d <<= 1) e += __shfl_xor(e, d, 64);
        if (tid == 0) {
            bmax[blockIdx.x] = m;
            bsum[blockIdx.x] = e;
        }
    }
}

// ---------------------------------------------------------------------------
// Kernel B: combine per-block (max, sumexp) -> global max & softmax denom
// ---------------------------------------------------------------------------
__global__ __launch_bounds__(256) void softmax_reduce_kernel(
    const float* __restrict__ bmax, const float* __restrict__ bsum,
    float* __restrict__ red, int nb)
{
    __shared__ float sm[4];
    __shared__ float ss[4];
    const int tid = threadIdx.x;

    float m = -1e30f;
    for (int i = tid; i < nb; i += 256) m = fmaxf(m, bmax[i]);
#pragma unroll
    for (int d = 1; d < 64; d <<= 1) m = fmaxf(m, __shfl_xor(m, d, 64));
    if ((tid & 63) == 0) sm[tid >> 6] = m;
    __syncthreads();
    const float gmax = fmaxf(fmaxf(sm[0], sm[1]), fmaxf(sm[2], sm[3]));

    float s = 0.f;
    for (int i = tid; i < nb; i += 256) s += bsum[i] * __expf(bmax[i] - gmax);
#pragma unroll
    for (int d = 1; d < 64; d <<= 1) s += __shfl_xor(s, d, 64);
    if ((tid & 63) == 0) ss[tid >> 6] = s;
    __syncthreads();
    if (tid == 0) {
        red[0] = gmax;
        red[1] = ss[0] + ss[1] + ss[2] + ss[3];
    }
}

// ---------------------------------------------------------------------------
// Kernel E: per-graph weighted mean. batch_index sorted -> binary search the
// [start, end) row range; one block per graph, one thread per column.
// ---------------------------------------------------------------------------
__device__ __forceinline__ int lower_bound(const int* __restrict__ a, int n, int key)
{
    int lo = 0, hi = n;
    while (lo < hi) {
        int mid = (lo + hi) >> 1;
        if (a[mid] < key) lo = mid + 1; else hi = mid;
    }
    return lo;
}

__global__ __launch_bounds__(256) void pool_kernel(
    const float* __restrict__ z, const int* __restrict__ bidx,
    const float* __restrict__ scores, const float* __restrict__ red,
    float* __restrict__ out, int N)
{
    const int g   = blockIdx.x;
    const int col = threadIdx.x;
    __shared__ int se[2];
    if (col == 0) {
        se[0] = lower_bound(bidx, N, g);
        se[1] = lower_bound(bidx, N, g + 1);
    }
    __syncthreads();
    const int start = se[0], end = se[1];
    const float gmax    = red[0];
    const float inv_den = 1.0f / red[1];

    float a0 = 0.f, a1 = 0.f, a2 = 0.f, a3 = 0.f;
    int i = start;
    for (; i + 3 < end; i += 4) {
        const float w0 = __expf(scores[i]     - gmax);
        const float w1 = __expf(scores[i + 1] - gmax);
        const float w2 = __expf(scores[i + 2] - gmax);
        const float w3 = __expf(scores[i + 3] - gmax);
        a0 += w0 * z[(size_t)i * IN_DIM + col];
        a1 += w1 * z[(size_t)(i + 1) * IN_DIM + col];
        a2 += w2 * z[(size_t)(i + 2) * IN_DIM + col];
        a3 += w3 * z[(size_t)(i + 3) * IN_DIM + col];
    }
    for (; i < end; ++i)
        a0 += __expf(scores[i] - gmax) * z[(size_t)i * IN_DIM + col];

    const float acc = (a0 + a1) + (a2 + a3);
    const int cnt = end - start;
    out[(size_t)g * POOL_DIM + col] = acc * inv_den / fmaxf((float)cnt, 1.0f);
}

// ---------------------------------------------------------------------------
extern "C" void kernel_launch(void* const* d_in, const int* in_sizes, int n_in,
                              void* d_out, int out_size, void* d_ws, size_t ws_size,
                              hipStream_t stream)
{
    const float* z    = (const float*)d_in[0];
    const int*   bidx = (const int*)  d_in[1];
    const float* W1   = (const float*)d_in[2];
    const float* b1   = (const float*)d_in[3];
    const float* W2   = (const float*)d_in[4];
    const float* b2   = (const float*)d_in[5];
    float*       out  = (float*)d_out;

    const int N  = in_sizes[0] / IN_DIM;       // 200000
    const int G  = out_size / POOL_DIM;        // 2000
    const int nb = (N + RPB - 1) / RPB;        // 1563

    // workspace layout (16B-aligned slots)
    float*  scores = (float*)d_ws;             // N floats
    float*  bmax   = scores + 200000;          // pad region: nb <= 1600
    float*  bsum   = bmax + 1600;
    float*  red    = bsum + 1600;
    ushort* W1h    = (ushort*)(red + 16);
    ushort* W1l    = W1h + HID * IN_DIM;

    split_w1_kernel<<<(HID * IN_DIM + 255) / 256, 256, 0, stream>>>(
        W1, W1h, W1l, HID * IN_DIM);
    attn_scores_mfma<<<nb, 256, 0, stream>>>(z, W1h, W1l, b1, W2, b2,
                                             scores, bmax, bsum, N);
    softmax_reduce_kernel<<<1, 256, 0, stream>>>(bmax, bsum, red, nb);
    pool_kernel<<<G, 256, 0, stream>>>(z, bidx, scores, red, out, N);
}

// Round 5
// 213.831 us; speedup vs baseline: 32.0999x; 1.0267x over previous
//
#include <hip/hip_runtime.h>

#define IN_DIM   320
#define POOL_DIM 256
#define HID      128
#define RPB      128            // rows per block (4 waves x 32 rows)
#define NKC      10             // 320 / 32

typedef __attribute__((ext_vector_type(8))) short bf16x8;
typedef __attribute__((ext_vector_type(4))) float f32x4;

__device__ __forceinline__ unsigned fbits(float f) {
    union { float f; unsigned u; } c; c.f = f; return c.u;
}
// pack bf16(trunc) of two f32 bit patterns: low16 = u0>>16, high16 = u1>>16
__device__ __forceinline__ unsigned pack2(unsigned u0, unsigned u1) {
    return __builtin_amdgcn_perm(u1, u0, 0x07060302u);
}

// split 8 f32 into hi(trunc-bf16) + lo(bf16 of residual); hi+lo ~ f32 exact
// to ~2^-16 relative.
__device__ __forceinline__ void split8(float4 a, float4 b, bf16x8& hi, bf16x8& lo) {
    float f[8] = { a.x, a.y, a.z, a.w, b.x, b.y, b.z, b.w };
    unsigned hu[8], lu[8];
#pragma unroll
    for (int i = 0; i < 8; ++i) {
        unsigned u = fbits(f[i]);
        hu[i] = u;
        float hif = __builtin_bit_cast(float, u & 0xffff0000u);
        lu[i] = fbits(f[i] - hif);
    }
    int4 hp, lp;
    hp.x = pack2(hu[0], hu[1]); hp.y = pack2(hu[2], hu[3]);
    hp.z = pack2(hu[4], hu[5]); hp.w = pack2(hu[6], hu[7]);
    lp.x = pack2(lu[0], lu[1]); lp.y = pack2(lu[2], lu[3]);
    lp.z = pack2(lu[4], lu[5]); lp.w = pack2(lu[6], lu[7]);
    hi = __builtin_bit_cast(bf16x8, hp);
    lo = __builtin_bit_cast(bf16x8, lp);
}

// ---------------------------------------------------------------------------
// One-time: split W1 into interleaved hi/lo bf16: Ws[h][0:320]=hi, [320:640]=lo
// ---------------------------------------------------------------------------
__global__ __launch_bounds__(256) void split_w1_kernel(
    const float* __restrict__ W1, ushort* __restrict__ Ws, int n)
{
    int i = blockIdx.x * 256 + threadIdx.x;
    if (i < n) {
        int h = i / IN_DIM, k = i - h * IN_DIM;
        float f = W1[i];
        unsigned u = fbits(f);
        float hif = __builtin_bit_cast(float, u & 0xffff0000u);
        Ws[h * 640 + k]       = (ushort)(u >> 16);
        Ws[h * 640 + 320 + k] = (ushort)(fbits(f - hif) >> 16);
    }
}

// ---------------------------------------------------------------------------
// Kernel A (MFMA, split-bf16, depth-2 z prefetch): no LDS/barriers in loop.
// Per iter kc:  B) W loads(kc) + MFMAs on frags prepared at D(kc-1)
//               C) issue z loads for kc+2      (AFTER all awaited loads ->
//                  counted vmcnt for W never drains the z prefetch)
//               D) split8(z[kc+1]) -> frags for next iter
// mfma_f32_16x16x32_bf16: A row=l&15, k=(l>>4)*8+j; C/D col=l&15,
// row=(l>>4)*4+reg.  3-term split product (drop lo*lo).
// ---------------------------------------------------------------------------
__global__ __launch_bounds__(256) void attn_scores_mfma(
    const float* __restrict__ z, const ushort* __restrict__ Ws,
    const float* __restrict__ b1, const float* __restrict__ W2,
    const float* __restrict__ b2,
    float* __restrict__ scores, float* __restrict__ bmax,
    float* __restrict__ bsum, int N)
{
    __shared__ float sblk[RPB];

    const int tid  = threadIdx.x;
    const int wid  = tid >> 6;
    const int lane = tid & 63;
    const int lm   = lane & 15;
    const int lg   = lane >> 4;
    const int r0   = blockIdx.x * RPB;
    const int wr0  = r0 + wid * 32;

    int row0 = wr0 + lm;      if (row0 > N - 1) row0 = N - 1;
    int row1 = wr0 + 16 + lm; if (row1 > N - 1) row1 = N - 1;
    const float*  zp0 = z  + (size_t)row0 * IN_DIM + lg * 8;
    const float*  zp1 = z  + (size_t)row1 * IN_DIM + lg * 8;
    const ushort* wp  = Ws + (size_t)lm * 640 + lg * 8;

    f32x4 acc[2][8];
#pragma unroll
    for (int rt = 0; rt < 2; ++rt)
#pragma unroll
        for (int ht = 0; ht < 8; ++ht) acc[rt][ht] = (f32x4){0.f, 0.f, 0.f, 0.f};

    // z raw double-buffer + a-frag double-buffer (all statically indexed
    // after full unroll; runtime indexing would go to scratch)
    float4 zraw[2][4];
    bf16x8 af[2][4];   // [buf][a0h,a0l,a1h,a1l]

    {   // prologue: load z[0], z[1]; split z[0]
        const float4* p0 = (const float4*)zp0;
        const float4* p1 = (const float4*)zp1;
        zraw[0][0] = p0[0]; zraw[0][1] = p0[1];
        zraw[0][2] = p1[0]; zraw[0][3] = p1[1];
        const float4* q0 = (const float4*)(zp0 + 32);
        const float4* q1 = (const float4*)(zp1 + 32);
        zraw[1][0] = q0[0]; zraw[1][1] = q0[1];
        zraw[1][2] = q1[0]; zraw[1][3] = q1[1];
        split8(zraw[0][0], zraw[0][1], af[0][0], af[0][1]);
        split8(zraw[0][2], zraw[0][3], af[0][2], af[0][3]);
    }

#pragma unroll
    for (int kc = 0; kc < NKC; ++kc) {
        const int cb = kc & 1;          // constant after unroll
        const int nb2 = (kc + 1) & 1;
        const int ko = kc * 32;

        // B: W loads + MFMAs (frags ready since last iter)
#pragma unroll
        for (int ht = 0; ht < 8; ++ht) {
            const ushort* wb = wp + (size_t)ht * 10240 + ko;
            const bf16x8 bh = *(const bf16x8*)(wb);
            const bf16x8 bl = *(const bf16x8*)(wb + 320);
            acc[0][ht] = __builtin_amdgcn_mfma_f32_16x16x32_bf16(af[cb][0], bh, acc[0][ht], 0, 0, 0);
            acc[0][ht] = __builtin_amdgcn_mfma_f32_16x16x32_bf16(af[cb][1], bh, acc[0][ht], 0, 0, 0);
            acc[0][ht] = __builtin_amdgcn_mfma_f32_16x16x32_bf16(af[cb][0], bl, acc[0][ht], 0, 0, 0);
            acc[1][ht] = __builtin_amdgcn_mfma_f32_16x16x32_bf16(af[cb][2], bh, acc[1][ht], 0, 0, 0);
            acc[1][ht] = __builtin_amdgcn_mfma_f32_16x16x32_bf16(af[cb][3], bh, acc[1][ht], 0, 0, 0);
            acc[1][ht] = __builtin_amdgcn_mfma_f32_16x16x32_bf16(af[cb][2], bl, acc[1][ht], 0, 0, 0);
        }

        // C: issue z prefetch for kc+2 (overwrites raw buffer already split)
        if (kc + 2 < NKC) {
            const int ko2 = (kc + 2) * 32;
            const float4* p0 = (const float4*)(zp0 + ko2);
            const float4* p1 = (const float4*)(zp1 + ko2);
            zraw[cb][0] = p0[0]; zraw[cb][1] = p0[1];
            zraw[cb][2] = p1[0]; zraw[cb][3] = p1[1];
        }

        // D: split z[kc+1] -> frags for next iter
        if (kc + 1 < NKC) {
            split8(zraw[nb2][0], zraw[nb2][1], af[nb2][0], af[nb2][1]);
            split8(zraw[nb2][2], zraw[nb2][3], af[nb2][2], af[nb2][3]);
        }
    }

    // ---- epilogue: relu + dot(W2) per lane-col, reduce over 16 cols
    float b1v[8], w2v[8];
#pragma unroll
    for (int ht = 0; ht < 8; ++ht) {
        b1v[ht] = b1[ht * 16 + lm];
        w2v[ht] = W2[ht * 16 + lm];
    }
    const float b2v = b2[0];

#pragma unroll
    for (int rt = 0; rt < 2; ++rt) {
#pragma unroll
        for (int reg = 0; reg < 4; ++reg) {
            float s = 0.f;
#pragma unroll
            for (int ht = 0; ht < 8; ++ht)
                s += fmaxf(acc[rt][ht][reg] + b1v[ht], 0.f) * w2v[ht];
            s += __shfl_xor(s, 1);
            s += __shfl_xor(s, 2);
            s += __shfl_xor(s, 4);
            s += __shfl_xor(s, 8);
            s += b2v;
            if (lm == 0) {
                const int rloc = wid * 32 + rt * 16 + lg * 4 + reg;
                const int grow = r0 + rloc;
                if (grow < N) {
                    scores[grow] = s;
                    sblk[rloc] = s;
                } else {
                    sblk[rloc] = -1e30f;
                }
            }
        }
    }
    __syncthreads();

    // ---- block (max, sum-exp): 128 scores folded into one wave
    if (tid < 64) {
        const float v0 = sblk[tid];
        const float v1 = sblk[tid + 64];
        float m = fmaxf(v0, v1);
#pragma unroll
        for (int d = 1; d < 64; d <<= 1) m = fmaxf(m, __shfl_xor(m, d, 64));
        float e = __expf(v0 - m) + __expf(v1 - m);
#pragma unroll
        for (int d = 1; d < 64; d <<= 1) e += __shfl_xor(e, d, 64);
        if (tid == 0) {
            bmax[blockIdx.x] = m;
            bsum[blockIdx.x] = e;
        }
    }
}

// ---------------------------------------------------------------------------
// Kernel B: combine per-block (max, sumexp) -> global max & softmax denom
// ---------------------------------------------------------------------------
__global__ __launch_bounds__(256) void softmax_reduce_kernel(
    const float* __restrict__ bmax, const float* __restrict__ bsum,
    float* __restrict__ red, int nb)
{
    __shared__ float sm[4];
    __shared__ float ss[4];
    const int tid = threadIdx.x;

    float m = -1e30f;
    for (int i = tid; i < nb; i += 256) m = fmaxf(m, bmax[i]);
#pragma unroll
    for (int d = 1; d < 64; d <<= 1) m = fmaxf(m, __shfl_xor(m, d, 64));
    if ((tid & 63) == 0) sm[tid >> 6] = m;
    __syncthreads();
    const float gmax = fmaxf(fmaxf(sm[0], sm[1]), fmaxf(sm[2], sm[3]));

    float s = 0.f;
    for (int i = tid; i < nb; i += 256) s += bsum[i] * __expf(bmax[i] - gmax);
#pragma unroll
    for (int d = 1; d < 64; d <<= 1) s += __shfl_xor(s, d, 64);
    if ((tid & 63) == 0) ss[tid >> 6] = s;
    __syncthreads();
    if (tid == 0) {
        red[0] = gmax;
        red[1] = ss[0] + ss[1] + ss[2] + ss[3];
    }
}

// ---------------------------------------------------------------------------
// Kernel E: per-graph weighted mean. batch_index sorted -> binary search the
// [start, end) row range; one block per graph, one thread per column.
// ---------------------------------------------------------------------------
__device__ __forceinline__ int lower_bound(const int* __restrict__ a, int n, int key)
{
    int lo = 0, hi = n;
    while (lo < hi) {
        int mid = (lo + hi) >> 1;
        if (a[mid] < key) lo = mid + 1; else hi = mid;
    }
    return lo;
}

__global__ __launch_bounds__(256) void pool_kernel(
    const float* __restrict__ z, const int* __restrict__ bidx,
    const float* __restrict__ scores, const float* __restrict__ red,
    float* __restrict__ out, int N)
{
    const int g   = blockIdx.x;
    const int col = threadIdx.x;
    __shared__ int se[2];
    if (col == 0) {
        se[0] = lower_bound(bidx, N, g);
        se[1] = lower_bound(bidx, N, g + 1);
    }
    __syncthreads();
    const int start = se[0], end = se[1];
    const float gmax    = red[0];
    const float inv_den = 1.0f / red[1];

    float a0 = 0.f, a1 = 0.f, a2 = 0.f, a3 = 0.f;
    int i = start;
    for (; i + 3 < end; i += 4) {
        const float w0 = __expf(scores[i]     - gmax);
        const float w1 = __expf(scores[i + 1] - gmax);
        const float w2 = __expf(scores[i + 2] - gmax);
        const float w3 = __expf(scores[i + 3] - gmax);
        a0 += w0 * z[(size_t)i * IN_DIM + col];
        a1 += w1 * z[(size_t)(i + 1) * IN_DIM + col];
        a2 += w2 * z[(size_t)(i + 2) * IN_DIM + col];
        a3 += w3 * z[(size_t)(i + 3) * IN_DIM + col];
    }
    for (; i < end; ++i)
        a0 += __expf(scores[i] - gmax) * z[(size_t)i * IN_DIM + col];

    const float acc = (a0 + a1) + (a2 + a3);
    const int cnt = end - start;
    out[(size_t)g * POOL_DIM + col] = acc * inv_den / fmaxf((float)cnt, 1.0f);
}

// ---------------------------------------------------------------------------
extern "C" void kernel_launch(void* const* d_in, const int* in_sizes, int n_in,
                              void* d_out, int out_size, void* d_ws, size_t ws_size,
                              hipStream_t stream)
{
    const float* z    = (const float*)d_in[0];
    const int*   bidx = (const int*)  d_in[1];
    const float* W1   = (const float*)d_in[2];
    const float* b1   = (const float*)d_in[3];
    const float* W2   = (const float*)d_in[4];
    const float* b2   = (const float*)d_in[5];
    float*       out  = (float*)d_out;

    const int N  = in_sizes[0] / IN_DIM;       // 200000
    const int G  = out_size / POOL_DIM;        // 2000
    const int nb = (N + RPB - 1) / RPB;        // 1563

    // workspace layout (16B-aligned slots)
    float*  scores = (float*)d_ws;             // N floats
    float*  bmax   = scores + 200000;          // pad region: nb <= 1600
    float*  bsum   = bmax + 1600;
    float*  red    = bsum + 1600;
    ushort* Ws     = (ushort*)(red + 16);      // HID*640 ushorts = 160 KB

    split_w1_kernel<<<(HID * IN_DIM + 255) / 256, 256, 0, stream>>>(
        W1, Ws, HID * IN_DIM);
    attn_scores_mfma<<<nb, 256, 0, stream>>>(z, Ws, b1, W2, b2,
                                             scores, bmax, bsum, N);
    softmax_reduce_kernel<<<1, 256, 0, stream>>>(bmax, bsum, red, nb);
    pool_kernel<<<G, 256, 0, stream>>>(z, bidx, scores, red, out, N);
}

// Round 6
// 142.882 us; speedup vs baseline: 48.0393x; 1.4966x over previous
//
#include <hip/hip_runtime.h>

#define IN_DIM   320
#define POOL_DIM 256
#define HID      128
#define RPB      128            // rows per block (4 waves x 32 rows)
#define NKC      10             // 320 / 32

typedef __attribute__((ext_vector_type(8))) short bf16x8;
typedef __attribute__((ext_vector_type(4))) float f32x4;

__device__ __forceinline__ unsigned fbits(float f) {
    union { float f; unsigned u; } c; c.f = f; return c.u;
}
// pack bf16(trunc) of two f32 bit patterns: low16 = u0>>16, high16 = u1>>16
__device__ __forceinline__ unsigned pack2(unsigned u0, unsigned u1) {
    return __builtin_amdgcn_perm(u1, u0, 0x07060302u);
}

// split 8 f32 into hi(trunc-bf16) + lo(bf16 of residual); hi+lo ~ f32 exact
// to ~2^-16 relative.
__device__ __forceinline__ void split8(float4 a, float4 b, bf16x8& hi, bf16x8& lo) {
    float f[8] = { a.x, a.y, a.z, a.w, b.x, b.y, b.z, b.w };
    unsigned hu[8], lu[8];
#pragma unroll
    for (int i = 0; i < 8; ++i) {
        unsigned u = fbits(f[i]);
        hu[i] = u;
        float hif = __builtin_bit_cast(float, u & 0xffff0000u);
        lu[i] = fbits(f[i] - hif);
    }
    int4 hp, lp;
    hp.x = pack2(hu[0], hu[1]); hp.y = pack2(hu[2], hu[3]);
    hp.z = pack2(hu[4], hu[5]); hp.w = pack2(hu[6], hu[7]);
    lp.x = pack2(lu[0], lu[1]); lp.y = pack2(lu[2], lu[3]);
    lp.z = pack2(lu[4], lu[5]); lp.w = pack2(lu[6], lu[7]);
    hi = __builtin_bit_cast(bf16x8, hp);
    lo = __builtin_bit_cast(bf16x8, lp);
}

// ---------------------------------------------------------------------------
// One-time: pack W1 into MFMA B-fragment order, split hi/lo:
//   Wpk[((kc*16 + ht*2 + s)*64 + lane)*8 + j] =
//       split_s( W1[h = ht*16 + (lane&15)][k = kc*32 + (lane>>4)*8 + j] )
// so the main loop's B-load is base + lane*16B  -> perfectly coalesced.
// ---------------------------------------------------------------------------
__global__ __launch_bounds__(256) void pack_w1_kernel(
    const float* __restrict__ W1, ushort* __restrict__ Wpk)
{
    const int i = blockIdx.x * 256 + threadIdx.x;   // one bf16x8 group each
    if (i >= NKC * 8 * 2 * 64) return;
    const int kc   = i >> 10;
    const int r    = i & 1023;
    const int ht   = r >> 7;
    const int r2   = r & 127;
    const int s    = r2 >> 6;
    const int lane = r2 & 63;
    const int h    = ht * 16 + (lane & 15);
    const int k0   = kc * 32 + (lane >> 4) * 8;

    ushort v[8];
#pragma unroll
    for (int j = 0; j < 8; ++j) {
        const float f = W1[(size_t)h * IN_DIM + k0 + j];
        const unsigned u = fbits(f);
        if (s == 0) {
            v[j] = (ushort)(u >> 16);
        } else {
            const float hif = __builtin_bit_cast(float, u & 0xffff0000u);
            v[j] = (ushort)(fbits(f - hif) >> 16);
        }
    }
    ushort* dst = Wpk + (size_t)i * 8;
#pragma unroll
    for (int j = 0; j < 8; ++j) dst[j] = v[j];
}

// ---------------------------------------------------------------------------
// Kernel A (MFMA, split-bf16, fragment-packed W): no LDS/barriers in loop.
// Per iter kc: B) coalesced W-frag loads + MFMAs on frags from D(kc-1)
//              C) issue z prefetch for kc+2
//              D) split8(z[kc+1]) -> frags for next iter
// mfma_f32_16x16x32_bf16: A row=l&15, k=(l>>4)*8+j; C/D col=l&15,
// row=(l>>4)*4+reg.  3-term split product (drop lo*lo).
// ---------------------------------------------------------------------------
__global__ __launch_bounds__(256) void attn_scores_mfma(
    const float* __restrict__ z, const ushort* __restrict__ Wpk,
    const float* __restrict__ b1, const float* __restrict__ W2,
    const float* __restrict__ b2,
    float* __restrict__ scores, float* __restrict__ bmax,
    float* __restrict__ bsum, int N)
{
    __shared__ float sblk[RPB];

    const int tid  = threadIdx.x;
    const int wid  = tid >> 6;
    const int lane = tid & 63;
    const int lm   = lane & 15;
    const int lg   = lane >> 4;
    const int r0   = blockIdx.x * RPB;
    const int wr0  = r0 + wid * 32;

    int row0 = wr0 + lm;      if (row0 > N - 1) row0 = N - 1;
    int row1 = wr0 + 16 + lm; if (row1 > N - 1) row1 = N - 1;
    const float*  zp0 = z   + (size_t)row0 * IN_DIM + lg * 8;
    const float*  zp1 = z   + (size_t)row1 * IN_DIM + lg * 8;
    const ushort* wp  = Wpk + (size_t)lane * 8;     // coalesced frag base

    f32x4 acc[2][8];
#pragma unroll
    for (int rt = 0; rt < 2; ++rt)
#pragma unroll
        for (int ht = 0; ht < 8; ++ht) acc[rt][ht] = (f32x4){0.f, 0.f, 0.f, 0.f};

    // z raw double-buffer + a-frag double-buffer (statically indexed after
    // full unroll; runtime indexing would go to scratch)
    float4 zraw[2][4];
    bf16x8 af[2][4];   // [buf][a0h,a0l,a1h,a1l]

    {   // prologue: load z[0], z[1]; split z[0]
        const float4* p0 = (const float4*)zp0;
        const float4* p1 = (const float4*)zp1;
        zraw[0][0] = p0[0]; zraw[0][1] = p0[1];
        zraw[0][2] = p1[0]; zraw[0][3] = p1[1];
        const float4* q0 = (const float4*)(zp0 + 32);
        const float4* q1 = (const float4*)(zp1 + 32);
        zraw[1][0] = q0[0]; zraw[1][1] = q0[1];
        zraw[1][2] = q1[0]; zraw[1][3] = q1[1];
        split8(zraw[0][0], zraw[0][1], af[0][0], af[0][1]);
        split8(zraw[0][2], zraw[0][3], af[0][2], af[0][3]);
    }

#pragma unroll
    for (int kc = 0; kc < NKC; ++kc) {
        const int cb  = kc & 1;          // constant after unroll
        const int nb2 = (kc + 1) & 1;

        // B: coalesced W-frag loads + MFMAs (frags ready since last iter)
#pragma unroll
        for (int ht = 0; ht < 8; ++ht) {
            const ushort* wb = wp + (size_t)(kc * 16 + ht * 2) * 512;
            const bf16x8 bh = *(const bf16x8*)(wb);
            const bf16x8 bl = *(const bf16x8*)(wb + 512);
            acc[0][ht] = __builtin_amdgcn_mfma_f32_16x16x32_bf16(af[cb][0], bh, acc[0][ht], 0, 0, 0);
            acc[0][ht] = __builtin_amdgcn_mfma_f32_16x16x32_bf16(af[cb][1], bh, acc[0][ht], 0, 0, 0);
            acc[0][ht] = __builtin_amdgcn_mfma_f32_16x16x32_bf16(af[cb][0], bl, acc[0][ht], 0, 0, 0);
            acc[1][ht] = __builtin_amdgcn_mfma_f32_16x16x32_bf16(af[cb][2], bh, acc[1][ht], 0, 0, 0);
            acc[1][ht] = __builtin_amdgcn_mfma_f32_16x16x32_bf16(af[cb][3], bh, acc[1][ht], 0, 0, 0);
            acc[1][ht] = __builtin_amdgcn_mfma_f32_16x16x32_bf16(af[cb][2], bl, acc[1][ht], 0, 0, 0);
        }

        // C: issue z prefetch for kc+2 (overwrites raw buffer already split)
        if (kc + 2 < NKC) {
            const int ko2 = (kc + 2) * 32;
            const float4* p0 = (const float4*)(zp0 + ko2);
            const float4* p1 = (const float4*)(zp1 + ko2);
            zraw[cb][0] = p0[0]; zraw[cb][1] = p0[1];
            zraw[cb][2] = p1[0]; zraw[cb][3] = p1[1];
        }

        // D: split z[kc+1] -> frags for next iter
        if (kc + 1 < NKC) {
            split8(zraw[nb2][0], zraw[nb2][1], af[nb2][0], af[nb2][1]);
            split8(zraw[nb2][2], zraw[nb2][3], af[nb2][2], af[nb2][3]);
        }
    }

    // ---- epilogue: relu + dot(W2) per lane-col, reduce over 16 cols
    float b1v[8], w2v[8];
#pragma unroll
    for (int ht = 0; ht < 8; ++ht) {
        b1v[ht] = b1[ht * 16 + lm];
        w2v[ht] = W2[ht * 16 + lm];
    }
    const float b2v = b2[0];

#pragma unroll
    for (int rt = 0; rt < 2; ++rt) {
#pragma unroll
        for (int reg = 0; reg < 4; ++reg) {
            float s = 0.f;
#pragma unroll
            for (int ht = 0; ht < 8; ++ht)
                s += fmaxf(acc[rt][ht][reg] + b1v[ht], 0.f) * w2v[ht];
            s += __shfl_xor(s, 1);
            s += __shfl_xor(s, 2);
            s += __shfl_xor(s, 4);
            s += __shfl_xor(s, 8);
            s += b2v;
            if (lm == 0) {
                const int rloc = wid * 32 + rt * 16 + lg * 4 + reg;
                const int grow = r0 + rloc;
                if (grow < N) {
                    scores[grow] = s;
                    sblk[rloc] = s;
                } else {
                    sblk[rloc] = -1e30f;
                }
            }
        }
    }
    __syncthreads();

    // ---- block (max, sum-exp): 128 scores folded into one wave
    if (tid < 64) {
        const float v0 = sblk[tid];
        const float v1 = sblk[tid + 64];
        float m = fmaxf(v0, v1);
#pragma unroll
        for (int d = 1; d < 64; d <<= 1) m = fmaxf(m, __shfl_xor(m, d, 64));
        float e = __expf(v0 - m) + __expf(v1 - m);
#pragma unroll
        for (int d = 1; d < 64; d <<= 1) e += __shfl_xor(e, d, 64);
        if (tid == 0) {
            bmax[blockIdx.x] = m;
            bsum[blockIdx.x] = e;
        }
    }
}

// ---------------------------------------------------------------------------
// Kernel B: combine per-block (max, sumexp) -> global max & softmax denom
// ---------------------------------------------------------------------------
__global__ __launch_bounds__(256) void softmax_reduce_kernel(
    const float* __restrict__ bmax, const float* __restrict__ bsum,
    float* __restrict__ red, int nb)
{
    __shared__ float sm[4];
    __shared__ float ss[4];
    const int tid = threadIdx.x;

    float m = -1e30f;
    for (int i = tid; i < nb; i += 256) m = fmaxf(m, bmax[i]);
#pragma unroll
    for (int d = 1; d < 64; d <<= 1) m = fmaxf(m, __shfl_xor(m, d, 64));
    if ((tid & 63) == 0) sm[tid >> 6] = m;
    __syncthreads();
    const float gmax = fmaxf(fmaxf(sm[0], sm[1]), fmaxf(sm[2], sm[3]));

    float s = 0.f;
    for (int i = tid; i < nb; i += 256) s += bsum[i] * __expf(bmax[i] - gmax);
#pragma unroll
    for (int d = 1; d < 64; d <<= 1) s += __shfl_xor(s, d, 64);
    if ((tid & 63) == 0) ss[tid >> 6] = s;
    __syncthreads();
    if (tid == 0) {
        red[0] = gmax;
        red[1] = ss[0] + ss[1] + ss[2] + ss[3];
    }
}

// ---------------------------------------------------------------------------
// Kernel E: per-graph weighted mean, float4-vectorized.
// Block = 256 threads = 4 row-groups x 64 float4-lanes (256 cols).
// Lanes read consecutive float4 -> coalesced 1KB per row access.
// ---------------------------------------------------------------------------
__device__ __forceinline__ int lower_bound(const int* __restrict__ a, int n, int key)
{
    int lo = 0, hi = n;
    while (lo < hi) {
        int mid = (lo + hi) >> 1;
        if (a[mid] < key) lo = mid + 1; else hi = mid;
    }
    return lo;
}

__global__ __launch_bounds__(256) void pool_kernel(
    const float* __restrict__ z, const int* __restrict__ bidx,
    const float* __restrict__ scores, const float* __restrict__ red,
    float* __restrict__ out, int N)
{
    const int g    = blockIdx.x;
    const int lane = threadIdx.x & 63;   // float4 column
    const int rg   = threadIdx.x >> 6;   // row-group 0..3
    __shared__ int se[2];
    __shared__ f32x4 pred[4][64];

    if (threadIdx.x == 0) {
        se[0] = lower_bound(bidx, N, g);
        se[1] = lower_bound(bidx, N, g + 1);
    }
    __syncthreads();
    const int start = se[0], end = se[1];
    const float gmax    = red[0];
    const float inv_den = 1.0f / red[1];

    const f32x4* zf = (const f32x4*)z;   // 80 f32x4 per row; use first 64

    f32x4 acc = (f32x4){0.f, 0.f, 0.f, 0.f};
    for (int i = start + rg; i < end; i += 4) {
        const float w = __expf(scores[i] - gmax);
        acc += w * zf[(size_t)i * 80 + lane];
    }
    pred[rg][lane] = acc;
    __syncthreads();

    if (rg == 0) {
        const f32x4 s = (pred[0][lane] + pred[1][lane]) +
                        (pred[2][lane] + pred[3][lane]);
        const int cnt = end - start;
        const float sc = inv_den / fmaxf((float)cnt, 1.0f);
        ((f32x4*)out)[(size_t)g * 64 + lane] = s * sc;
    }
}

// ---------------------------------------------------------------------------
extern "C" void kernel_launch(void* const* d_in, const int* in_sizes, int n_in,
                              void* d_out, int out_size, void* d_ws, size_t ws_size,
                              hipStream_t stream)
{
    const float* z    = (const float*)d_in[0];
    const int*   bidx = (const int*)  d_in[1];
    const float* W1   = (const float*)d_in[2];
    const float* b1   = (const float*)d_in[3];
    const float* W2   = (const float*)d_in[4];
    const float* b2   = (const float*)d_in[5];
    float*       out  = (float*)d_out;

    const int N  = in_sizes[0] / IN_DIM;       // 200000
    const int G  = out_size / POOL_DIM;        // 2000
    const int nb = (N + RPB - 1) / RPB;        // 1563

    // workspace layout (16B-aligned slots)
    float*  scores = (float*)d_ws;             // N floats
    float*  bmax   = scores + 200000;          // pad region: nb <= 1600
    float*  bsum   = bmax + 1600;
    float*  red    = bsum + 1600;
    ushort* Wpk    = (ushort*)(red + 16);      // NKC*8*2*64*8 shorts = 160 KB

    pack_w1_kernel<<<(NKC * 8 * 2 * 64 + 255) / 256, 256, 0, stream>>>(W1, Wpk);
    attn_scores_mfma<<<nb, 256, 0, stream>>>(z, Wpk, b1, W2, b2,
                                             scores, bmax, bsum, N);
    softmax_reduce_kernel<<<1, 256, 0, stream>>>(bmax, bsum, red, nb);
    pool_kernel<<<G, 256, 0, stream>>>(z, bidx, scores, red, out, N);
}

// Round 7
// 110.407 us; speedup vs baseline: 62.1695x; 1.2941x over previous
//
#include <hip/hip_runtime.h>

#define IN_DIM   320
#define POOL_DIM 256
#define HID      128
#define RPB      128            // rows per block (4 waves x 32 rows)
#define NKC      10             // 320 / 32

typedef __attribute__((ext_vector_type(8))) short bf16x8;
typedef __attribute__((ext_vector_type(4))) float f32x4;

typedef __attribute__((address_space(1))) const unsigned int guint;
typedef __attribute__((address_space(3))) unsigned int luint;

__device__ __forceinline__ void gl_lds16(const void* g, void* l) {
    __builtin_amdgcn_global_load_lds((guint*)g, (luint*)l, 16, 0, 0);
}

__device__ __forceinline__ unsigned fbits(float f) {
    union { float f; unsigned u; } c; c.f = f; return c.u;
}
// pack bf16(trunc) of two f32 bit patterns: low16 = u0>>16, high16 = u1>>16
__device__ __forceinline__ unsigned pack2(unsigned u0, unsigned u1) {
    return __builtin_amdgcn_perm(u1, u0, 0x07060302u);
}

// split 8 f32 into hi(trunc-bf16) + lo(bf16 of residual); hi+lo ~ f32 exact
// to ~2^-16 relative.
__device__ __forceinline__ void split8(float4 a, float4 b, bf16x8& hi, bf16x8& lo) {
    float f[8] = { a.x, a.y, a.z, a.w, b.x, b.y, b.z, b.w };
    unsigned hu[8], lu[8];
#pragma unroll
    for (int i = 0; i < 8; ++i) {
        unsigned u = fbits(f[i]);
        hu[i] = u;
        float hif = __builtin_bit_cast(float, u & 0xffff0000u);
        lu[i] = fbits(f[i] - hif);
    }
    int4 hp, lp;
    hp.x = pack2(hu[0], hu[1]); hp.y = pack2(hu[2], hu[3]);
    hp.z = pack2(hu[4], hu[5]); hp.w = pack2(hu[6], hu[7]);
    lp.x = pack2(lu[0], lu[1]); lp.y = pack2(lu[2], lu[3]);
    lp.z = pack2(lu[4], lu[5]); lp.w = pack2(lu[6], lu[7]);
    hi = __builtin_bit_cast(bf16x8, hp);
    lo = __builtin_bit_cast(bf16x8, lp);
}

// ---------------------------------------------------------------------------
// One-time: pack W1 into MFMA B-fragment order, split hi/lo (frag-linear):
//   Wpk[((kc*16 + ht*2 + s)*64 + lane)*8 + j] =
//       split_s( W1[h = ht*16 + (lane&15)][k = kc*32 + (lane>>4)*8 + j] )
// Frag-linear => the 16KB per-kc chunk can be DMA'd to LDS verbatim.
// ---------------------------------------------------------------------------
__global__ __launch_bounds__(256) void pack_w1_kernel(
    const float* __restrict__ W1, ushort* __restrict__ Wpk)
{
    const int i = blockIdx.x * 256 + threadIdx.x;   // one bf16x8 group each
    if (i >= NKC * 8 * 2 * 64) return;
    const int kc   = i >> 10;
    const int r    = i & 1023;
    const int ht   = r >> 7;
    const int r2   = r & 127;
    const int s    = r2 >> 6;
    const int lane = r2 & 63;
    const int h    = ht * 16 + (lane & 15);
    const int k0   = kc * 32 + (lane >> 4) * 8;

    ushort v[8];
#pragma unroll
    for (int j = 0; j < 8; ++j) {
        const float f = W1[(size_t)h * IN_DIM + k0 + j];
        const unsigned u = fbits(f);
        if (s == 0) {
            v[j] = (ushort)(u >> 16);
        } else {
            const float hif = __builtin_bit_cast(float, u & 0xffff0000u);
            v[j] = (ushort)(fbits(f - hif) >> 16);
        }
    }
    ushort* dst = Wpk + (size_t)i * 8;
#pragma unroll
    for (int j = 0; j < 8; ++j) dst[j] = v[j];
}

// ---------------------------------------------------------------------------
// Kernel A (MFMA, split-bf16, W double-buffered in LDS via global_load_lds):
// per kc: STAGE W[kc+1]->buf^1 (fire-and-forget DMA, no dest VGPRs ->
// unbounded pipeline depth); ds_read 16 W frags from buf; 48 MFMAs;
// z direct-prefetch depth 2; one barrier per kc.
// mfma_f32_16x16x32_bf16: A row=l&15, k=(l>>4)*8+j; C/D col=l&15,
// row=(l>>4)*4+reg.  3-term split product (drop lo*lo).
// ---------------------------------------------------------------------------
__global__ __launch_bounds__(256) void attn_scores_mfma(
    const float* __restrict__ z, const ushort* __restrict__ Wpk,
    const float* __restrict__ b1, const float* __restrict__ W2,
    const float* __restrict__ b2,
    float* __restrict__ scores, float* __restrict__ bmax,
    float* __restrict__ bsum, int N)
{
    __shared__ float4 wbuf[2][1024];   // 2 x 16 KB W-fragment buffers
    __shared__ float  sblk[RPB];

    const int tid  = threadIdx.x;
    const int wid  = tid >> 6;
    const int lane = tid & 63;
    const int lm   = lane & 15;
    const int lg   = lane >> 4;
    const int r0   = blockIdx.x * RPB;
    const int wr0  = r0 + wid * 32;

    int row0 = wr0 + lm;      if (row0 > N - 1) row0 = N - 1;
    int row1 = wr0 + 16 + lm; if (row1 > N - 1) row1 = N - 1;
    const float* zp0 = z + (size_t)row0 * IN_DIM + lg * 8;
    const float* zp1 = z + (size_t)row1 * IN_DIM + lg * 8;

    // staging: 16 KB per kc = 4 rounds x 256 threads x 16B; Wpk is
    // frag-linear so src byte off == LDS byte off (within the kc chunk)
    #define STAGE_W(kc_, b_)                                                  \
        { const char* src = (const char*)Wpk + (size_t)(kc_) * 16384;         \
          char* dst = (char*)&wbuf[b_][0];                                    \
          _Pragma("unroll")                                                   \
          for (int j = 0; j < 4; ++j) {                                       \
              const int o = (tid + j * 256) * 16;                             \
              gl_lds16(src + o, dst + o);                                     \
          } }

    f32x4 acc[2][8];
#pragma unroll
    for (int rt = 0; rt < 2; ++rt)
#pragma unroll
        for (int ht = 0; ht < 8; ++ht) acc[rt][ht] = (f32x4){0.f, 0.f, 0.f, 0.f};

    // z raw double-buffer + a-frag double-buffer (statically indexed after
    // full unroll)
    float4 zraw[2][4];
    bf16x8 af[2][4];   // [buf][a0h,a0l,a1h,a1l]

    STAGE_W(0, 0);

    {   // prologue: load z[0], z[1]; split z[0]
        const float4* p0 = (const float4*)zp0;
        const float4* p1 = (const float4*)zp1;
        zraw[0][0] = p0[0]; zraw[0][1] = p0[1];
        zraw[0][2] = p1[0]; zraw[0][3] = p1[1];
        const float4* q0 = (const float4*)(zp0 + 32);
        const float4* q1 = (const float4*)(zp1 + 32);
        zraw[1][0] = q0[0]; zraw[1][1] = q0[1];
        zraw[1][2] = q1[0]; zraw[1][3] = q1[1];
        split8(zraw[0][0], zraw[0][1], af[0][0], af[0][1]);
        split8(zraw[0][2], zraw[0][3], af[0][2], af[0][3]);
    }
    __syncthreads();   // W[0] staged (compiler inserts vmcnt(0) first)

#pragma unroll
    for (int kc = 0; kc < NKC; ++kc) {
        const int cb  = kc & 1;          // constant after unroll
        const int nb2 = cb ^ 1;

        // issue next W stage early (writes buf^1; its readers finished
        // before the barrier that ended iter kc-1)
        if (kc + 1 < NKC) STAGE_W(kc + 1, nb2);

        // ds_read W frags + MFMAs (A-frags ready since last iter)
        const char* wb_base = (const char*)&wbuf[cb][0] + lane * 16;
#pragma unroll
        for (int ht = 0; ht < 8; ++ht) {
            const bf16x8 bh = *(const bf16x8*)(wb_base + ht * 2048);
            const bf16x8 bl = *(const bf16x8*)(wb_base + ht * 2048 + 1024);
            acc[0][ht] = __builtin_amdgcn_mfma_f32_16x16x32_bf16(af[cb][0], bh, acc[0][ht], 0, 0, 0);
            acc[0][ht] = __builtin_amdgcn_mfma_f32_16x16x32_bf16(af[cb][1], bh, acc[0][ht], 0, 0, 0);
            acc[0][ht] = __builtin_amdgcn_mfma_f32_16x16x32_bf16(af[cb][0], bl, acc[0][ht], 0, 0, 0);
            acc[1][ht] = __builtin_amdgcn_mfma_f32_16x16x32_bf16(af[cb][2], bh, acc[1][ht], 0, 0, 0);
            acc[1][ht] = __builtin_amdgcn_mfma_f32_16x16x32_bf16(af[cb][3], bh, acc[1][ht], 0, 0, 0);
            acc[1][ht] = __builtin_amdgcn_mfma_f32_16x16x32_bf16(af[cb][2], bl, acc[1][ht], 0, 0, 0);
        }

        // z prefetch for kc+2 (overwrites raw buffer already split)
        if (kc + 2 < NKC) {
            const int ko2 = (kc + 2) * 32;
            const float4* p0 = (const float4*)(zp0 + ko2);
            const float4* p1 = (const float4*)(zp1 + ko2);
            zraw[cb][0] = p0[0]; zraw[cb][1] = p0[1];
            zraw[cb][2] = p1[0]; zraw[cb][3] = p1[1];
        }

        // split z[kc+1] -> frags for next iter
        if (kc + 1 < NKC) {
            split8(zraw[nb2][0], zraw[nb2][1], af[nb2][0], af[nb2][1]);
            split8(zraw[nb2][2], zraw[nb2][3], af[nb2][2], af[nb2][3]);
            __syncthreads();   // W[kc+1] staged; buf readers done
        }
    }

    // ---- epilogue: relu + dot(W2) per lane-col, reduce over 16 cols
    float b1v[8], w2v[8];
#pragma unroll
    for (int ht = 0; ht < 8; ++ht) {
        b1v[ht] = b1[ht * 16 + lm];
        w2v[ht] = W2[ht * 16 + lm];
    }
    const float b2v = b2[0];

#pragma unroll
    for (int rt = 0; rt < 2; ++rt) {
#pragma unroll
        for (int reg = 0; reg < 4; ++reg) {
            float s = 0.f;
#pragma unroll
            for (int ht = 0; ht < 8; ++ht)
                s += fmaxf(acc[rt][ht][reg] + b1v[ht], 0.f) * w2v[ht];
            s += __shfl_xor(s, 1);
            s += __shfl_xor(s, 2);
            s += __shfl_xor(s, 4);
            s += __shfl_xor(s, 8);
            s += b2v;
            if (lm == 0) {
                const int rloc = wid * 32 + rt * 16 + lg * 4 + reg;
                const int grow = r0 + rloc;
                if (grow < N) {
                    scores[grow] = s;
                    sblk[rloc] = s;
                } else {
                    sblk[rloc] = -1e30f;
                }
            }
        }
    }
    __syncthreads();

    // ---- block (max, sum-exp): 128 scores folded into one wave
    if (tid < 64) {
        const float v0 = sblk[tid];
        const float v1 = sblk[tid + 64];
        float m = fmaxf(v0, v1);
#pragma unroll
        for (int d = 1; d < 64; d <<= 1) m = fmaxf(m, __shfl_xor(m, d, 64));
        float e = __expf(v0 - m) + __expf(v1 - m);
#pragma unroll
        for (int d = 1; d < 64; d <<= 1) e += __shfl_xor(e, d, 64);
        if (tid == 0) {
            bmax[blockIdx.x] = m;
            bsum[blockIdx.x] = e;
        }
    }
}

// ---------------------------------------------------------------------------
// Kernel B: combine per-block (max, sumexp) -> global max & softmax denom
// ---------------------------------------------------------------------------
__global__ __launch_bounds__(256) void softmax_reduce_kernel(
    const float* __restrict__ bmax, const float* __restrict__ bsum,
    float* __restrict__ red, int nb)
{
    __shared__ float sm[4];
    __shared__ float ss[4];
    const int tid = threadIdx.x;

    float m = -1e30f;
    for (int i = tid; i < nb; i += 256) m = fmaxf(m, bmax[i]);
#pragma unroll
    for (int d = 1; d < 64; d <<= 1) m = fmaxf(m, __shfl_xor(m, d, 64));
    if ((tid & 63) == 0) sm[tid >> 6] = m;
    __syncthreads();
    const float gmax = fmaxf(fmaxf(sm[0], sm[1]), fmaxf(sm[2], sm[3]));

    float s = 0.f;
    for (int i = tid; i < nb; i += 256) s += bsum[i] * __expf(bmax[i] - gmax);
#pragma unroll
    for (int d = 1; d < 64; d <<= 1) s += __shfl_xor(s, d, 64);
    if ((tid & 63) == 0) ss[tid >> 6] = s;
    __syncthreads();
    if (tid == 0) {
        red[0] = gmax;
        red[1] = ss[0] + ss[1] + ss[2] + ss[3];
    }
}

// ---------------------------------------------------------------------------
// Kernel E: per-graph weighted mean, float4-vectorized.
// Block = 256 threads = 4 row-groups x 64 float4-lanes (256 cols).
// ---------------------------------------------------------------------------
__device__ __forceinline__ int lower_bound(const int* __restrict__ a, int n, int key)
{
    int lo = 0, hi = n;
    while (lo < hi) {
        int mid = (lo + hi) >> 1;
        if (a[mid] < key) lo = mid + 1; else hi = mid;
    }
    return lo;
}

__global__ __launch_bounds__(256) void pool_kernel(
    const float* __restrict__ z, const int* __restrict__ bidx,
    const float* __restrict__ scores, const float* __restrict__ red,
    float* __restrict__ out, int N)
{
    const int g    = blockIdx.x;
    const int lane = threadIdx.x & 63;   // float4 column
    const int rg   = threadIdx.x >> 6;   // row-group 0..3
    __shared__ int se[2];
    __shared__ f32x4 pred[4][64];

    if (threadIdx.x == 0) {
        se[0] = lower_bound(bidx, N, g);
        se[1] = lower_bound(bidx, N, g + 1);
    }
    __syncthreads();
    const int start = se[0], end = se[1];
    const float gmax    = red[0];
    const float inv_den = 1.0f / red[1];

    const f32x4* zf = (const f32x4*)z;   // 80 f32x4 per row; use first 64

    f32x4 acc = (f32x4){0.f, 0.f, 0.f, 0.f};
    for (int i = start + rg; i < end; i += 4) {
        const float w = __expf(scores[i] - gmax);
        acc += w * zf[(size_t)i * 80 + lane];
    }
    pred[rg][lane] = acc;
    __syncthreads();

    if (rg == 0) {
        const f32x4 s = (pred[0][lane] + pred[1][lane]) +
                        (pred[2][lane] + pred[3][lane]);
        const int cnt = end - start;
        const float sc = inv_den / fmaxf((float)cnt, 1.0f);
        ((f32x4*)out)[(size_t)g * 64 + lane] = s * sc;
    }
}

// ---------------------------------------------------------------------------
extern "C" void kernel_launch(void* const* d_in, const int* in_sizes, int n_in,
                              void* d_out, int out_size, void* d_ws, size_t ws_size,
                              hipStream_t stream)
{
    const float* z    = (const float*)d_in[0];
    const int*   bidx = (const int*)  d_in[1];
    const float* W1   = (const float*)d_in[2];
    const float* b1   = (const float*)d_in[3];
    const float* W2   = (const float*)d_in[4];
    const float* b2   = (const float*)d_in[5];
    float*       out  = (float*)d_out;

    const int N  = in_sizes[0] / IN_DIM;       // 200000
    const int G  = out_size / POOL_DIM;        // 2000
    const int nb = (N + RPB - 1) / RPB;        // 1563

    // workspace layout (16B-aligned slots)
    float*  scores = (float*)d_ws;             // N floats
    float*  bmax   = scores + 200000;          // pad region: nb <= 1600
    float*  bsum   = bmax + 1600;
    float*  red    = bsum + 1600;
    ushort* Wpk    = (ushort*)(red + 16);      // NKC*8*2*64*8 shorts = 160 KB

    pack_w1_kernel<<<(NKC * 8 * 2 * 64 + 255) / 256, 256, 0, stream>>>(W1, Wpk);
    attn_scores_mfma<<<nb, 256, 0, stream>>>(z, Wpk, b1, W2, b2,
                                             scores, bmax, bsum, N);
    softmax_reduce_kernel<<<1, 256, 0, stream>>>(bmax, bsum, red, nb);
    pool_kernel<<<G, 256, 0, stream>>>(z, bidx, scores, red, out, N);
}